// Round 1
// baseline (426.226 us; speedup 1.0000x reference)
//
#include <hip/hip_runtime.h>
#include <math.h>

// Softmax over last axis: 65536 rows x 1024 fp32.
// One wave (64 lanes) per row; 16 floats/lane held in registers as 4x float4.
// Single pass over memory: load -> max-reduce -> exp -> sum-reduce -> scale -> store.

__global__ __launch_bounds__(256) void softmax_rows_1024(
    const float* __restrict__ x, float* __restrict__ out, int nrows) {
    const int gtid = blockIdx.x * blockDim.x + threadIdx.x;
    const int wave = gtid >> 6;          // global wave id = row id
    const int lane = threadIdx.x & 63;
    if (wave >= nrows) return;

    const float* __restrict__ row  = x   + (size_t)wave * 1024;
    float* __restrict__       orow = out + (size_t)wave * 1024;

    // Coalesced: chunk c covers floats [c*256, c*256+256); lane i takes 4 floats.
    float4 v[4];
#pragma unroll
    for (int c = 0; c < 4; ++c)
        v[c] = *reinterpret_cast<const float4*>(row + c * 256 + lane * 4);

    // Per-lane max
    float m = fmaxf(fmaxf(v[0].x, v[0].y), fmaxf(v[0].z, v[0].w));
#pragma unroll
    for (int c = 1; c < 4; ++c)
        m = fmaxf(m, fmaxf(fmaxf(v[c].x, v[c].y), fmaxf(v[c].z, v[c].w)));

    // Wave-wide max reduce (64 lanes)
#pragma unroll
    for (int off = 32; off >= 1; off >>= 1)
        m = fmaxf(m, __shfl_xor(m, off, 64));

    // exp(x - m) and per-lane sum
    float s = 0.0f;
#pragma unroll
    for (int c = 0; c < 4; ++c) {
        v[c].x = __expf(v[c].x - m);
        v[c].y = __expf(v[c].y - m);
        v[c].z = __expf(v[c].z - m);
        v[c].w = __expf(v[c].w - m);
        s += (v[c].x + v[c].y) + (v[c].z + v[c].w);
    }

    // Wave-wide sum reduce
#pragma unroll
    for (int off = 32; off >= 1; off >>= 1)
        s += __shfl_xor(s, off, 64);

    const float inv = 1.0f / s;

#pragma unroll
    for (int c = 0; c < 4; ++c) {
        float4 o;
        o.x = v[c].x * inv;
        o.y = v[c].y * inv;
        o.z = v[c].z * inv;
        o.w = v[c].w * inv;
        *reinterpret_cast<float4*>(orow + c * 256 + lane * 4) = o;
    }
}

extern "C" void kernel_launch(void* const* d_in, const int* in_sizes, int n_in,
                              void* d_out, int out_size, void* d_ws, size_t ws_size,
                              hipStream_t stream) {
    const float* x = (const float*)d_in[0];
    float* out = (float*)d_out;
    const int nrows = in_sizes[0] / 1024;          // 65536
    const int block = 256;                          // 4 waves = 4 rows per block
    const int grid = (nrows * 64 + block - 1) / block;
    softmax_rows_1024<<<grid, block, 0, stream>>>(x, out, nrows);
}